// Round 9
// baseline (147.398 us; speedup 1.0000x reference)
//
#include <hip/hip_runtime.h>

typedef _Float16 half8 __attribute__((ext_vector_type(8)));
typedef float floatx16 __attribute__((ext_vector_type(16)));

#define TPB   256            // 4 waves; each wave owns ONE 32-query A-frag
#define RPTS  1024           // db points per round (32 KiB LDS image)
#define NTILE (RPTS / 32)    // 32 tiles of 32 db points per round
#define SMH   (RPTS * 16)    // 16384 halfs = 32 KiB

// ---------- fused pack: build B-frag images for BOTH clouds + zero out ----------
// Per point (32 halfs): khalf0 = (xh,xl,xh,yh,yl,yh,zh,zl), khalf1 = (zh,hqh,hql,0..)
// tile t (32 pts): 512 halfs; col c: khalf0 at t*512+c*8, khalf1 +256.
__global__ __launch_bounds__(256) void pack_all(const float* __restrict__ xyz1,
                                                const float* __restrict__ xyz2,
                                                _Float16* __restrict__ frag1,
                                                _Float16* __restrict__ frag2,
                                                float* __restrict__ out,
                                                int N, int M, int B,
                                                int p1pad, int p2pad) {
    const int b = blockIdx.y;
    const int z = blockIdx.z;                       // 0: cloud1, 1: cloud2
    const int p = blockIdx.x * 256 + (int)threadIdx.x;

    if (z == 0 && b == 0 && blockIdx.x == 0) {
        for (int i = (int)threadIdx.x; i < B; i += 256) out[i] = 0.0f;
    }

    const int npts = z ? M : N;
    const int npad = z ? p2pad : p1pad;
    if (p >= npad) return;
    const float* src = z ? xyz2 : xyz1;
    _Float16*    dst = z ? frag2 : frag1;

    const int g = p < npts ? p : npts - 1;          // clamp-pad: dups never change a min
    const float* sp = src + ((size_t)b * npts + g) * 3;
    float x = sp[0], y = sp[1], zc = sp[2];
    float hq = 0.5f * (x * x + y * y + zc * zc);
    _Float16 xh = (_Float16)x, yh = (_Float16)y, zh = (_Float16)zc;
    _Float16 xl = (_Float16)(x - (float)xh);
    _Float16 yl = (_Float16)(y - (float)yh);
    _Float16 zl = (_Float16)(zc - (float)zh);
    _Float16 qh = (_Float16)hq;
    _Float16 ql = (_Float16)(hq - (float)qh);
    const _Float16 hz = (_Float16)0.0f;
    half8 v0, v1;
    v0[0] = xh; v0[1] = xl; v0[2] = xh; v0[3] = yh;
    v0[4] = yl; v0[5] = yh; v0[6] = zh; v0[7] = zl;
    v1[0] = zh; v1[1] = qh; v1[2] = ql; v1[3] = hz;
    v1[4] = hz; v1[5] = hz; v1[6] = hz; v1[7] = hz;
    int t = p >> 5, c = p & 31;
    _Float16* base = dst + (size_t)b * npad * 16 + (size_t)t * 512 + c * 8;
    *(half8*)base         = v0;
    *(half8*)(base + 256) = v1;
}

// ---------- main: 32x32x16 f16 MFMA, VGPR-form via inline asm ----------
// 128 queries/block (4 waves x 1 A-frag), full-db sweep -> per-query min is
// complete in-block -> atomicAdd epilogue, no dist array / reduce pass.
// A: (-xh,-xh,-xl,-yh,-yh,-yl,-zh,-zh | -zl, 1, 1, 0..) row m=lane&31, k=(lane>>5)*8+j
// acc = 0.5||q||^2 - p.q ; dist = 2*(ph + min acc).
// C/D: col=lane&31, row=(reg&3)+8*(reg>>2)+4*(lane>>5).
__global__ __launch_bounds__(TPB, 4) void chamfer_main(const float* __restrict__ xyz1,
                                                       const float* __restrict__ xyz2,
                                                       const _Float16* __restrict__ frag1,
                                                       const _Float16* __restrict__ frag2,
                                                       float* __restrict__ out,
                                                       int N, int M,
                                                       int p1pad, int p2pad) {
    const int b = blockIdx.y, dir = blockIdx.z;
    const float*    __restrict__ P = dir ? xyz2 + (size_t)b * M * 3 : xyz1 + (size_t)b * N * 3;
    const _Float16* __restrict__ F = dir ? frag1 + (size_t)b * p1pad * 16
                                         : frag2 + (size_t)b * p2pad * 16;
    const int nq    = dir ? M : N;
    const int mdpad = dir ? p1pad : p2pad;

    if ((int)blockIdx.x * 128 >= nq) return;   // block-uniform, before any barrier

    __shared__ __align__(16) _Float16 smB[SMH];

    const int tid = (int)threadIdx.x;
    const int w   = tid >> 6;
    const int l   = tid & 63;
    const int m   = l & 31;      // A row / B col this lane serves
    const int h   = l >> 5;      // k-half: k = h*8 + j

    const _Float16 hz = (_Float16)0.0f, hone = (_Float16)1.0f;
    const int qb = blockIdx.x * 128 + w * 32;

    // ---- Build the wave's A-fragment ----
    half8 afr;
    {
        int idx = qb + m;
        int ci  = idx < nq ? idx : nq - 1;
        float x = P[3 * ci], y = P[3 * ci + 1], z = P[3 * ci + 2];
        _Float16 xh = (_Float16)x, yh = (_Float16)y, zh = (_Float16)z;
        _Float16 xl = (_Float16)(x - (float)xh);
        _Float16 yl = (_Float16)(y - (float)yh);
        _Float16 zl = (_Float16)(z - (float)zh);
        if (h == 0) {
            afr[0] = -xh; afr[1] = -xh; afr[2] = -xl; afr[3] = -yh;
            afr[4] = -yh; afr[5] = -yl; afr[6] = -zh; afr[7] = -zh;
        } else {
            afr[0] = -zl; afr[1] = hone; afr[2] = hone; afr[3] = hz;
            afr[4] = hz;  afr[5] = hz;   afr[6] = hz;  afr[7] = hz;
        }
    }

    float rm[16];
#pragma unroll
    for (int i = 0; i < 16; ++i) rm[i] = 3.0e38f;

    const int nrounds = mdpad / RPTS;
    const _Float16* bp = smB + h * 256 + m * 8;

    for (int r = 0; r < nrounds; ++r) {
        if (r) __syncthreads();   // WAR guard before restaging
        // ---- Stage 32 KiB prepacked image: pure int4 copy ----
        const int4* __restrict__ gsrc = (const int4*)(F + (size_t)r * SMH);
        int4* __restrict__ ldst = (int4*)smB;
#pragma unroll
        for (int k = 0; k < (SMH * 2 / 16) / TPB; ++k) {   // 8 chunks/thread
            int c = k * TPB + tid;
            ldst[c] = gsrc[c];
        }
        __syncthreads();

        // ---- Sweep: 2 tiles/iter, VGPR-dest MFMA pair, min3 fold ----
        for (int t = 0; t < NTILE; t += 2) {
            half8 b0 = *(const half8*)(bp + t * 512);
            half8 b1 = *(const half8*)(bp + t * 512 + 512);
            floatx16 d0, d1;
            // "=&v": early-clobber VGPR dests (D must not alias A/B while the
            // 16-pass MFMA reads them). s_nop x3 = 24 cyc covers the
            // MFMA->VALU D-read hazard (~18 cyc) for both results.
            asm("v_mfma_f32_32x32x16_f16 %0, %2, %3, 0\n\t"
                "v_mfma_f32_32x32x16_f16 %1, %2, %4, 0\n\t"
                "s_nop 7\n\t"
                "s_nop 7\n\t"
                "s_nop 7"
                : "=&v"(d0), "=&v"(d1)
                : "v"(afr), "v"(b0), "v"(b1));
#pragma unroll
            for (int i = 0; i < 16; ++i)
                rm[i] = fminf(fminf(rm[i], d0[i]), d1[i]);   // -> v_min3
        }
    }

    // ---- Col-min across the 32 lanes of each k-half (offsets don't touch bit5) ----
#pragma unroll
    for (int off = 1; off < 32; off <<= 1) {
#pragma unroll
        for (int i = 0; i < 16; ++i) rm[i] = fminf(rm[i], __shfl_xor(rm[i], off, 64));
    }

    // ---- Emit: lanes m<16 of each half own one row; recompute ph from P ----
    float s = 0.0f;
    if (m < 16) {
        const int reg = (m & 3) + 4 * (m >> 2);
        const int row = 4 * h + (m & 3) + 8 * (m >> 2);
        const int idx = qb + row;
        if (idx < nq) {
            float v = rm[0];
#pragma unroll
            for (int r2 = 1; r2 < 16; ++r2) v = (reg == r2) ? rm[r2] : v;
            float x = P[3 * idx], y = P[3 * idx + 1], z = P[3 * idx + 2];
            s = v + 0.5f * (x * x + y * y + z * z);
        }
    }
#pragma unroll
    for (int off = 32; off > 0; off >>= 1) s += __shfl_down(s, off, 64);
    if (l == 0) atomicAdd(out + b, s * (2.0f / (float)nq));   // dist = 2*(ph+acc)
}

// ---------- fallback (ws too small): proven R5 kernel ----------
__global__ __launch_bounds__(TPB, 4) void chamfer_plain(const float* __restrict__ xyz1,
                                                        const float* __restrict__ xyz2,
                                                        float* __restrict__ out,
                                                        int N, int M) {
    const int b = blockIdx.y, dir = blockIdx.z;
    const float* __restrict__ P = dir ? xyz2 + (size_t)b * M * 3 : xyz1 + (size_t)b * N * 3;
    const float* __restrict__ Q = dir ? xyz1 + (size_t)b * N * 3 : xyz2 + (size_t)b * M * 3;
    const int nq = dir ? M : N;
    const int md = dir ? N : M;
    if ((int)blockIdx.x * TPB >= nq) return;
    __shared__ __align__(16) _Float16 smB[SMH];
    const int tid = (int)threadIdx.x;
    const int w = tid >> 6, l = tid & 63, m = l & 31, h = l >> 5;
    const _Float16 hz = (_Float16)0.0f, hone = (_Float16)1.0f;
    const int qb = blockIdx.x * 256 + w * 64;
    half8 afr[2];
#pragma unroll
    for (int g = 0; g < 2; ++g) {
        int idx = qb + g * 32 + m;
        int ci  = idx < nq ? idx : nq - 1;
        float x = P[3 * ci], y = P[3 * ci + 1], z = P[3 * ci + 2];
        _Float16 xh = (_Float16)x, yh = (_Float16)y, zh = (_Float16)z;
        _Float16 xl = (_Float16)(x - (float)xh);
        _Float16 yl = (_Float16)(y - (float)yh);
        _Float16 zl = (_Float16)(z - (float)zh);
        half8 a;
        if (h == 0) { a[0]=-xh;a[1]=-xh;a[2]=-xl;a[3]=-yh;a[4]=-yh;a[5]=-yl;a[6]=-zh;a[7]=-zh; }
        else        { a[0]=-zl;a[1]=hone;a[2]=hone;a[3]=hz;a[4]=hz;a[5]=hz;a[6]=hz;a[7]=hz; }
        afr[g] = a;
    }
    float rm[32];
#pragma unroll
    for (int i = 0; i < 32; ++i) rm[i] = 3.0e38f;
    const floatx16 czero = {0,0,0,0,0,0,0,0,0,0,0,0,0,0,0,0};
    const int nrounds = (md + RPTS - 1) / RPTS;
    const _Float16* bp = smB + h * 256 + m * 8;
    for (int r = 0; r < nrounds; ++r) {
        if (r) __syncthreads();
#pragma unroll
        for (int k = 0; k < RPTS / TPB; ++k) {
            int j = tid + k * TPB;
            int g = r * RPTS + j;
            g = g < md ? g : md - 1;
            float x = Q[3 * g], y = Q[3 * g + 1], z = Q[3 * g + 2];
            float hq = 0.5f * (x * x + y * y + z * z);
            _Float16 xh = (_Float16)x, yh = (_Float16)y, zh = (_Float16)z;
            _Float16 xl = (_Float16)(x - (float)xh);
            _Float16 yl = (_Float16)(y - (float)yh);
            _Float16 zl = (_Float16)(z - (float)zh);
            _Float16 qh = (_Float16)hq;
            _Float16 ql = (_Float16)(hq - (float)qh);
            int t = j >> 5, c = j & 31;
            half8 v0, v1;
            v0[0]=xh;v0[1]=xl;v0[2]=xh;v0[3]=yh;v0[4]=yl;v0[5]=yh;v0[6]=zh;v0[7]=zl;
            v1[0]=zh;v1[1]=qh;v1[2]=ql;v1[3]=hz;v1[4]=hz;v1[5]=hz;v1[6]=hz;v1[7]=hz;
            *(half8*)&smB[t * 512 + c * 8]       = v0;
            *(half8*)&smB[t * 512 + 256 + c * 8] = v1;
        }
        __syncthreads();
        for (int t = 0; t < NTILE; t += 2) {
            half8 b0 = *(const half8*)(bp + t * 512);
            half8 b1 = *(const half8*)(bp + t * 512 + 512);
            floatx16 d0a = __builtin_amdgcn_mfma_f32_32x32x16_f16(afr[0], b0, czero, 0, 0, 0);
            floatx16 d0b = __builtin_amdgcn_mfma_f32_32x32x16_f16(afr[0], b1, czero, 0, 0, 0);
#pragma unroll
            for (int i = 0; i < 16; ++i) rm[i] = fminf(fminf(rm[i], d0a[i]), d0b[i]);
            floatx16 d1a = __builtin_amdgcn_mfma_f32_32x32x16_f16(afr[1], b0, czero, 0, 0, 0);
            floatx16 d1b = __builtin_amdgcn_mfma_f32_32x32x16_f16(afr[1], b1, czero, 0, 0, 0);
#pragma unroll
            for (int i = 0; i < 16; ++i) rm[16+i] = fminf(fminf(rm[16+i], d1a[i]), d1b[i]);
        }
    }
#pragma unroll
    for (int off = 1; off < 32; off <<= 1) {
#pragma unroll
        for (int i = 0; i < 32; ++i) rm[i] = fminf(rm[i], __shfl_xor(rm[i], off, 64));
    }
    float s = 0.0f;
    if (m < 16) {
        const int reg = (m & 3) + 4 * (m >> 2);
        const int row = 4 * h + (m & 3) + 8 * (m >> 2);
#pragma unroll
        for (int g = 0; g < 2; ++g) {
            int idx = qb + g * 32 + row;
            if (idx < nq) {
                float x = P[3 * idx], y = P[3 * idx + 1], z = P[3 * idx + 2];
                s += rm[g * 16 + reg] + 0.5f * (x * x + y * y + z * z);
            }
        }
    }
#pragma unroll
    for (int off = 32; off > 0; off >>= 1) s += __shfl_down(s, off, 64);
    if (l == 0) atomicAdd(out + b, s * (2.0f / (float)nq));
}

extern "C" void kernel_launch(void* const* d_in, const int* in_sizes, int n_in,
                              void* d_out, int out_size, void* d_ws, size_t ws_size,
                              hipStream_t stream) {
    const float* xyz1 = (const float*)d_in[0];
    const float* xyz2 = (const float*)d_in[1];
    float* out = (float*)d_out;

    const int B = out_size;
    const int N = in_sizes[0] / (3 * B);
    const int M = in_sizes[1] / (3 * B);
    const int qmax = N > M ? N : M;

    const int p1pad = ((N + RPTS - 1) / RPTS) * RPTS;
    const int p2pad = ((M + RPTS - 1) / RPTS) * RPTS;
    const int qpad  = p1pad > p2pad ? p1pad : p2pad;
    const size_t f1bytes = (size_t)B * p1pad * 32;   // 32 B per point image
    const size_t f2bytes = (size_t)B * p2pad * 32;

    if (ws_size >= f1bytes + f2bytes) {
        _Float16* frag1 = (_Float16*)d_ws;
        _Float16* frag2 = (_Float16*)((char*)d_ws + f1bytes);

        pack_all<<<dim3(qpad / 256, B, 2), dim3(256), 0, stream>>>(
            xyz1, xyz2, frag1, frag2, out, N, M, B, p1pad, p2pad);

        dim3 grid((qmax + 127) / 128, B, 2);
        chamfer_main<<<grid, dim3(TPB), 0, stream>>>(xyz1, xyz2, frag1, frag2, out,
                                                     N, M, p1pad, p2pad);
    } else {
        hipMemsetAsync(out, 0, (size_t)B * sizeof(float), stream);
        dim3 grid((qmax + 255) / 256, B, 2);
        chamfer_plain<<<grid, dim3(TPB), 0, stream>>>(xyz1, xyz2, out, N, M);
    }
}

// Round 10
// 120.126 us; speedup vs baseline: 1.2270x; 1.2270x over previous
//
#include <hip/hip_runtime.h>

typedef _Float16 half8 __attribute__((ext_vector_type(8)));
typedef float floatx16 __attribute__((ext_vector_type(16)));

#define TPB   256            // 4 waves; each wave owns TWO 32-query A-frags
#define RPTS  1024           // db points per round (32 KiB LDS image)
#define NTILE (RPTS / 32)    // 32 tiles of 32 db points per round
#define SMH   (RPTS * 16)    // 16384 halfs = 32 KiB

// VGPR-dest MFMA pair: D in arch VGPRs (no AGPR shuttle). Caller guarantees
// >=24 cycles of other work before reading d0/d1 (no HW interlock on MFMA->VALU).
__device__ __forceinline__ void mfma_pair(const half8& a, const half8& b0, const half8& b1,
                                          floatx16& d0, floatx16& d1) {
    asm("v_mfma_f32_32x32x16_f16 %0, %2, %3, 0\n\t"
        "v_mfma_f32_32x32x16_f16 %1, %2, %4, 0"
        : "=&v"(d0), "=&v"(d1)
        : "v"(a), "v"(b0), "v"(b1));
}
// Nop-tailed variant for the last group before the drain fold.
__device__ __forceinline__ void mfma_pair_nop(const half8& a, const half8& b0, const half8& b1,
                                              floatx16& d0, floatx16& d1) {
    asm("v_mfma_f32_32x32x16_f16 %0, %2, %3, 0\n\t"
        "v_mfma_f32_32x32x16_f16 %1, %2, %4, 0\n\t"
        "s_nop 7\n\t"
        "s_nop 7\n\t"
        "s_nop 7"
        : "=&v"(d0), "=&v"(d1)
        : "v"(a), "v"(b0), "v"(b1));
}

// ---------- fused pack: build B-frag images for BOTH clouds + zero out ----------
// Per point (32 halfs): khalf0 = (xh,xl,xh,yh,yl,yh,zh,zl), khalf1 = (zh,hqh,hql,0..)
// tile t (32 pts): 512 halfs; col c: khalf0 at t*512+c*8, khalf1 +256.
__global__ __launch_bounds__(256) void pack_all(const float* __restrict__ xyz1,
                                                const float* __restrict__ xyz2,
                                                _Float16* __restrict__ frag1,
                                                _Float16* __restrict__ frag2,
                                                float* __restrict__ out,
                                                int N, int M, int B,
                                                int p1pad, int p2pad) {
    const int b = blockIdx.y;
    const int z = blockIdx.z;                       // 0: cloud1, 1: cloud2
    const int p = blockIdx.x * 256 + (int)threadIdx.x;

    if (z == 0 && b == 0 && blockIdx.x == 0) {
        for (int i = (int)threadIdx.x; i < B; i += 256) out[i] = 0.0f;
    }

    const int npts = z ? M : N;
    const int npad = z ? p2pad : p1pad;
    if (p >= npad) return;
    const float* src = z ? xyz2 : xyz1;
    _Float16*    dst = z ? frag2 : frag1;

    const int g = p < npts ? p : npts - 1;          // clamp-pad: dups never change a min
    const float* sp = src + ((size_t)b * npts + g) * 3;
    float x = sp[0], y = sp[1], zc = sp[2];
    float hq = 0.5f * (x * x + y * y + zc * zc);
    _Float16 xh = (_Float16)x, yh = (_Float16)y, zh = (_Float16)zc;
    _Float16 xl = (_Float16)(x - (float)xh);
    _Float16 yl = (_Float16)(y - (float)yh);
    _Float16 zl = (_Float16)(zc - (float)zh);
    _Float16 qh = (_Float16)hq;
    _Float16 ql = (_Float16)(hq - (float)qh);
    const _Float16 hz = (_Float16)0.0f;
    half8 v0, v1;
    v0[0] = xh; v0[1] = xl; v0[2] = xh; v0[3] = yh;
    v0[4] = yl; v0[5] = yh; v0[6] = zh; v0[7] = zl;
    v1[0] = zh; v1[1] = qh; v1[2] = ql; v1[3] = hz;
    v1[4] = hz; v1[5] = hz; v1[6] = hz; v1[7] = hz;
    int t = p >> 5, c = p & 31;
    _Float16* base = dst + (size_t)b * npad * 16 + (size_t)t * 512 + c * 8;
    *(half8*)base         = v0;
    *(half8*)(base + 256) = v1;
}

// ---------- main: 32x32x16 f16 MFMA, VGPR dests, pipelined fold ----------
// 256 queries/block (4 waves x 2 A-frags), full-db sweep -> atomicAdd epilogue.
// A: (-xh,-xh,-xl,-yh,-yh,-yl,-zh,-zh | -zl, 1, 1, 0..) row m=lane&31, k=(lane>>5)*8+j
// acc = 0.5||q||^2 - p.q ; dist = 2*(ph + min acc).
// C/D: col=lane&31, row=(reg&3)+8*(reg>>2)+4*(lane>>5).
__global__ __launch_bounds__(TPB, 4) void chamfer_main(const float* __restrict__ xyz1,
                                                       const float* __restrict__ xyz2,
                                                       const _Float16* __restrict__ frag1,
                                                       const _Float16* __restrict__ frag2,
                                                       float* __restrict__ out,
                                                       int N, int M,
                                                       int p1pad, int p2pad) {
    const int b = blockIdx.y, dir = blockIdx.z;
    const float*    __restrict__ P = dir ? xyz2 + (size_t)b * M * 3 : xyz1 + (size_t)b * N * 3;
    const _Float16* __restrict__ F = dir ? frag1 + (size_t)b * p1pad * 16
                                         : frag2 + (size_t)b * p2pad * 16;
    const int nq    = dir ? M : N;
    const int mdpad = dir ? p1pad : p2pad;

    if ((int)blockIdx.x * 256 >= nq) return;   // block-uniform, before any barrier

    __shared__ __align__(16) _Float16 smB[SMH];

    const int tid = (int)threadIdx.x;
    const int w   = tid >> 6;
    const int l   = tid & 63;
    const int m   = l & 31;      // A row / B col this lane serves
    const int h   = l >> 5;      // k-half: k = h*8 + j

    const _Float16 hz = (_Float16)0.0f, hone = (_Float16)1.0f;
    const int qb = blockIdx.x * 256 + w * 64;

    // ---- Build the wave's 2 A-fragments ----
    half8 afr0, afr1;
#pragma unroll
    for (int g = 0; g < 2; ++g) {
        int idx = qb + g * 32 + m;
        int ci  = idx < nq ? idx : nq - 1;
        float x = P[3 * ci], y = P[3 * ci + 1], z = P[3 * ci + 2];
        _Float16 xh = (_Float16)x, yh = (_Float16)y, zh = (_Float16)z;
        _Float16 xl = (_Float16)(x - (float)xh);
        _Float16 yl = (_Float16)(y - (float)yh);
        _Float16 zl = (_Float16)(z - (float)zh);
        half8 a;
        if (h == 0) {
            a[0] = -xh; a[1] = -xh; a[2] = -xl; a[3] = -yh;
            a[4] = -yh; a[5] = -yl; a[6] = -zh; a[7] = -zh;
        } else {
            a[0] = -zl; a[1] = hone; a[2] = hone; a[3] = hz;
            a[4] = hz;  a[5] = hz;   a[6] = hz;  a[7] = hz;
        }
        if (g == 0) afr0 = a; else afr1 = a;
    }

    float rm[32];
#pragma unroll
    for (int i = 0; i < 32; ++i) rm[i] = 3.0e38f;

    const int nrounds = mdpad / RPTS;
    const _Float16* bp = smB + h * 256 + m * 8;

    for (int r = 0; r < nrounds; ++r) {
        if (r) __syncthreads();   // WAR guard before restaging
        // ---- Stage 32 KiB prepacked image: pure int4 copy ----
        const int4* __restrict__ gsrc = (const int4*)(F + (size_t)r * SMH);
        int4* __restrict__ ldst = (int4*)smB;
#pragma unroll
        for (int k = 0; k < (SMH * 2 / 16) / TPB; ++k) {   // 8 chunks/thread
            int c = k * TPB + tid;
            ldst[c] = gsrc[c];
        }
        __syncthreads();

        // ---- Pipelined sweep: fold trails MFMA issue by one group ----
        floatx16 g0a, g0b, g1a, g1b;
        {
            half8 b0 = *(const half8*)(bp);
            half8 b1 = *(const half8*)(bp + 512);
            mfma_pair(afr0, b0, b1, g0a, g0b);
            mfma_pair(afr1, b0, b1, g1a, g1b);
        }
        for (int t = 2; t < NTILE - 2; t += 2) {
            half8 n0 = *(const half8*)(bp + t * 512);
            half8 n1 = *(const half8*)(bp + t * 512 + 512);
#pragma unroll
            for (int i = 0; i < 16; ++i)
                rm[i] = fminf(fminf(rm[i], g0a[i]), g0b[i]);        // -> v_min3
            mfma_pair(afr0, n0, n1, g0a, g0b);
#pragma unroll
            for (int i = 0; i < 16; ++i)
                rm[16 + i] = fminf(fminf(rm[16 + i], g1a[i]), g1b[i]);
            mfma_pair(afr1, n0, n1, g1a, g1b);
        }
        {   // last tile pair: nop-tailed so the drain fold is hazard-safe
            half8 n0 = *(const half8*)(bp + (NTILE - 2) * 512);
            half8 n1 = *(const half8*)(bp + (NTILE - 2) * 512 + 512);
#pragma unroll
            for (int i = 0; i < 16; ++i)
                rm[i] = fminf(fminf(rm[i], g0a[i]), g0b[i]);
            mfma_pair(afr0, n0, n1, g0a, g0b);
#pragma unroll
            for (int i = 0; i < 16; ++i)
                rm[16 + i] = fminf(fminf(rm[16 + i], g1a[i]), g1b[i]);
            mfma_pair_nop(afr1, n0, n1, g1a, g1b);
        }
#pragma unroll
        for (int i = 0; i < 16; ++i) {
            rm[i]      = fminf(fminf(rm[i],      g0a[i]), g0b[i]);
            rm[16 + i] = fminf(fminf(rm[16 + i], g1a[i]), g1b[i]);
        }
    }

    // ---- Col-min across the 32 lanes of each k-half ----
#pragma unroll
    for (int off = 1; off < 32; off <<= 1) {
#pragma unroll
        for (int i = 0; i < 32; ++i) rm[i] = fminf(rm[i], __shfl_xor(rm[i], off, 64));
    }

    // ---- Emit: lanes m<16 of each half own one row each; recompute ph ----
    float s = 0.0f;
    if (m < 16) {
        const int reg = (m & 3) + 4 * (m >> 2);
        const int row = 4 * h + (m & 3) + 8 * (m >> 2);
#pragma unroll
        for (int g = 0; g < 2; ++g) {
            int idx = qb + g * 32 + row;
            if (idx < nq) {
                float v = rm[g * 16];
#pragma unroll
                for (int r2 = 1; r2 < 16; ++r2) v = (reg == r2) ? rm[g * 16 + r2] : v;
                float x = P[3 * idx], y = P[3 * idx + 1], z = P[3 * idx + 2];
                s += v + 0.5f * (x * x + y * y + z * z);
            }
        }
    }
#pragma unroll
    for (int off = 32; off > 0; off >>= 1) s += __shfl_down(s, off, 64);
    if (l == 0) atomicAdd(out + b, s * (2.0f / (float)nq));   // dist = 2*(ph+acc)
}

// ---------- fallback (ws too small): proven R5 kernel ----------
typedef float floatx16b __attribute__((ext_vector_type(16)));
__global__ __launch_bounds__(TPB, 4) void chamfer_plain(const float* __restrict__ xyz1,
                                                        const float* __restrict__ xyz2,
                                                        float* __restrict__ out,
                                                        int N, int M) {
    const int b = blockIdx.y, dir = blockIdx.z;
    const float* __restrict__ P = dir ? xyz2 + (size_t)b * M * 3 : xyz1 + (size_t)b * N * 3;
    const float* __restrict__ Q = dir ? xyz1 + (size_t)b * N * 3 : xyz2 + (size_t)b * M * 3;
    const int nq = dir ? M : N;
    const int md = dir ? N : M;
    if ((int)blockIdx.x * TPB >= nq) return;
    __shared__ __align__(16) _Float16 smB[SMH];
    const int tid = (int)threadIdx.x;
    const int w = tid >> 6, l = tid & 63, m = l & 31, h = l >> 5;
    const _Float16 hz = (_Float16)0.0f, hone = (_Float16)1.0f;
    const int qb = blockIdx.x * 256 + w * 64;
    half8 afr[2];
#pragma unroll
    for (int g = 0; g < 2; ++g) {
        int idx = qb + g * 32 + m;
        int ci  = idx < nq ? idx : nq - 1;
        float x = P[3 * ci], y = P[3 * ci + 1], z = P[3 * ci + 2];
        _Float16 xh = (_Float16)x, yh = (_Float16)y, zh = (_Float16)z;
        _Float16 xl = (_Float16)(x - (float)xh);
        _Float16 yl = (_Float16)(y - (float)yh);
        _Float16 zl = (_Float16)(z - (float)zh);
        half8 a;
        if (h == 0) { a[0]=-xh;a[1]=-xh;a[2]=-xl;a[3]=-yh;a[4]=-yh;a[5]=-yl;a[6]=-zh;a[7]=-zh; }
        else        { a[0]=-zl;a[1]=hone;a[2]=hone;a[3]=hz;a[4]=hz;a[5]=hz;a[6]=hz;a[7]=hz; }
        afr[g] = a;
    }
    float rm[32];
#pragma unroll
    for (int i = 0; i < 32; ++i) rm[i] = 3.0e38f;
    const floatx16b czero = {0,0,0,0,0,0,0,0,0,0,0,0,0,0,0,0};
    const int nrounds = (md + RPTS - 1) / RPTS;
    const _Float16* bp = smB + h * 256 + m * 8;
    for (int r = 0; r < nrounds; ++r) {
        if (r) __syncthreads();
#pragma unroll
        for (int k = 0; k < RPTS / TPB; ++k) {
            int j = tid + k * TPB;
            int g = r * RPTS + j;
            g = g < md ? g : md - 1;
            float x = Q[3 * g], y = Q[3 * g + 1], z = Q[3 * g + 2];
            float hq = 0.5f * (x * x + y * y + z * z);
            _Float16 xh = (_Float16)x, yh = (_Float16)y, zh = (_Float16)z;
            _Float16 xl = (_Float16)(x - (float)xh);
            _Float16 yl = (_Float16)(y - (float)yh);
            _Float16 zl = (_Float16)(z - (float)zh);
            _Float16 qh = (_Float16)hq;
            _Float16 ql = (_Float16)(hq - (float)qh);
            int t = j >> 5, c = j & 31;
            half8 v0, v1;
            v0[0]=xh;v0[1]=xl;v0[2]=xh;v0[3]=yh;v0[4]=yl;v0[5]=yh;v0[6]=zh;v0[7]=zl;
            v1[0]=zh;v1[1]=qh;v1[2]=ql;v1[3]=hz;v1[4]=hz;v1[5]=hz;v1[6]=hz;v1[7]=hz;
            *(half8*)&smB[t * 512 + c * 8]       = v0;
            *(half8*)&smB[t * 512 + 256 + c * 8] = v1;
        }
        __syncthreads();
        for (int t = 0; t < NTILE; t += 2) {
            half8 b0 = *(const half8*)(bp + t * 512);
            half8 b1 = *(const half8*)(bp + t * 512 + 512);
            floatx16b d0a = __builtin_amdgcn_mfma_f32_32x32x16_f16(afr[0], b0, czero, 0, 0, 0);
            floatx16b d0b = __builtin_amdgcn_mfma_f32_32x32x16_f16(afr[0], b1, czero, 0, 0, 0);
#pragma unroll
            for (int i = 0; i < 16; ++i) rm[i] = fminf(fminf(rm[i], d0a[i]), d0b[i]);
            floatx16b d1a = __builtin_amdgcn_mfma_f32_32x32x16_f16(afr[1], b0, czero, 0, 0, 0);
            floatx16b d1b = __builtin_amdgcn_mfma_f32_32x32x16_f16(afr[1], b1, czero, 0, 0, 0);
#pragma unroll
            for (int i = 0; i < 16; ++i) rm[16+i] = fminf(fminf(rm[16+i], d1a[i]), d1b[i]);
        }
    }
#pragma unroll
    for (int off = 1; off < 32; off <<= 1) {
#pragma unroll
        for (int i = 0; i < 32; ++i) rm[i] = fminf(rm[i], __shfl_xor(rm[i], off, 64));
    }
    float s = 0.0f;
    if (m < 16) {
        const int reg = (m & 3) + 4 * (m >> 2);
        const int row = 4 * h + (m & 3) + 8 * (m >> 2);
#pragma unroll
        for (int g = 0; g < 2; ++g) {
            int idx = qb + g * 32 + row;
            if (idx < nq) {
                float x = P[3 * idx], y = P[3 * idx + 1], z = P[3 * idx + 2];
                s += rm[g * 16 + reg] + 0.5f * (x * x + y * y + z * z);
            }
        }
    }
#pragma unroll
    for (int off = 32; off > 0; off >>= 1) s += __shfl_down(s, off, 64);
    if (l == 0) atomicAdd(out + b, s * (2.0f / (float)nq));
}

extern "C" void kernel_launch(void* const* d_in, const int* in_sizes, int n_in,
                              void* d_out, int out_size, void* d_ws, size_t ws_size,
                              hipStream_t stream) {
    const float* xyz1 = (const float*)d_in[0];
    const float* xyz2 = (const float*)d_in[1];
    float* out = (float*)d_out;

    const int B = out_size;
    const int N = in_sizes[0] / (3 * B);
    const int M = in_sizes[1] / (3 * B);
    const int qmax = N > M ? N : M;

    const int p1pad = ((N + RPTS - 1) / RPTS) * RPTS;
    const int p2pad = ((M + RPTS - 1) / RPTS) * RPTS;
    const int qpad  = p1pad > p2pad ? p1pad : p2pad;
    const size_t f1bytes = (size_t)B * p1pad * 32;   // 32 B per point image
    const size_t f2bytes = (size_t)B * p2pad * 32;

    if (ws_size >= f1bytes + f2bytes) {
        _Float16* frag1 = (_Float16*)d_ws;
        _Float16* frag2 = (_Float16*)((char*)d_ws + f1bytes);

        pack_all<<<dim3(qpad / 256, B, 2), dim3(256), 0, stream>>>(
            xyz1, xyz2, frag1, frag2, out, N, M, B, p1pad, p2pad);

        dim3 grid((qmax + 255) / 256, B, 2);
        chamfer_main<<<grid, dim3(TPB), 0, stream>>>(xyz1, xyz2, frag1, frag2, out,
                                                     N, M, p1pad, p2pad);
    } else {
        hipMemsetAsync(out, 0, (size_t)B * sizeof(float), stream);
        dim3 grid((qmax + 255) / 256, B, 2);
        chamfer_plain<<<grid, dim3(TPB), 0, stream>>>(xyz1, xyz2, out, N, M);
    }
}